// Round 1
// baseline (785.256 us; speedup 1.0000x reference)
//
#include <hip/hip_runtime.h>

// NNOpenSetClassifier: per-pixel nearest-template classification.
//   frame [8,16384,128] f32, templates [64,16384,128] f32, classes [64] int
// Outputs (concat, all f32): masked_pred [8,N,21], mask [8,N], ncm [8,N],
//                            min_d [8,N], neigh_classes [8,N]
// Memory-bound: ~614 MB traffic -> ~97 us floor at 6.3 TB/s.

#define NPIX      16384
#define DDIM      128
#define NT        64
#define NB        8
#define NCAT      21
#define THRESH    230.0f
#define TS_STRIDE 132   // 128 + 4 pad: keeps 16B alignment (132*4=528=33*16),
                        // rotates ds_read_b128 bank-quads -> balanced access

__global__ __launch_bounds__(256, 4) void nn_openset_kernel(
    const float* __restrict__ frame,   // [8, 16384, 128]
    const float* __restrict__ tmpl,    // [64, 16384, 128]
    const int*   __restrict__ tcls,    // [64]
    float* __restrict__ out)
{
    __shared__ float ts[NT * TS_STRIDE];   // 33792 B -> 4 blocks/CU
    const int n   = blockIdx.x;            // pixel index
    const int tid = threadIdx.x;

    // ---- Stage templates[:, n, :] (64x128 f32 = 32 KB) into LDS ----
    // 2048 float4 total, 8 per thread. Per wave-instr: 2 rows x 512B contiguous.
    #pragma unroll
    for (int i = 0; i < 8; ++i) {
        int q  = tid + (i << 8);        // float4 index 0..2047
        int t  = q >> 5;                // template row
        int c4 = (q & 31) << 2;         // float offset within row
        float4 v = *(const float4*)(tmpl + (size_t)t * (NPIX * DDIM)
                                         + (size_t)n * DDIM + c4);
        *(float4*)(&ts[t * TS_STRIDE + c4]) = v;
    }
    __syncthreads();

    // ---- Compute: wave w owns batch rows {2w, 2w+1}; lane = template t ----
    const int lane = tid & 63;
    const int wv   = __builtin_amdgcn_readfirstlane(tid >> 6);  // wave-uniform
    const int b0 = wv * 2, b1 = b0 + 1;
    const float* xp0 = frame + ((size_t)b0 * NPIX + n) * DDIM;
    const float* xp1 = frame + ((size_t)b1 * NPIX + n) * DDIM;
    const float* tsp = &ts[lane * TS_STRIDE];

    float acc0 = 0.0f, acc1 = 0.0f;
    #pragma unroll 8
    for (int kq = 0; kq < 32; ++kq) {
        float4 tv = *(const float4*)(tsp + (kq << 2));   // ds_read_b128, balanced
        float4 x0 = *(const float4*)(xp0 + (kq << 2));   // wave-uniform bcast load
        float4 x1 = *(const float4*)(xp1 + (kq << 2));
        float d;
        d = x0.x - tv.x; acc0 = fmaf(d, d, acc0);
        d = x0.y - tv.y; acc0 = fmaf(d, d, acc0);
        d = x0.z - tv.z; acc0 = fmaf(d, d, acc0);
        d = x0.w - tv.w; acc0 = fmaf(d, d, acc0);
        d = x1.x - tv.x; acc1 = fmaf(d, d, acc1);
        d = x1.y - tv.y; acc1 = fmaf(d, d, acc1);
        d = x1.z - tv.z; acc1 = fmaf(d, d, acc1);
        d = x1.w - tv.w; acc1 = fmaf(d, d, acc1);
    }

    // ---- Wave-wide min+argmin over t (tie -> lower t, = jnp.argmin) ----
    float v0 = acc0, v1 = acc1;
    int   i0 = lane, i1 = lane;
    #pragma unroll
    for (int off = 32; off > 0; off >>= 1) {
        float o0 = __shfl_xor(v0, off);
        int  oi0 = __shfl_xor(i0, off);
        if (o0 < v0 || (o0 == v0 && oi0 < i0)) { v0 = o0; i0 = oi0; }
        float o1 = __shfl_xor(v1, off);
        int  oi1 = __shfl_xor(i1, off);
        if (o1 < v1 || (o1 == v1 && oi1 < i1)) { v1 = o1; i1 = oi1; }
    }

    const int  cls0 = tcls[i0];
    const int  cls1 = tcls[i1];
    const bool m0 = (v0 <= THRESH);
    const bool m1 = (v1 <= THRESH);

    float* out0 = out;                                   // masked_pred [8,N,21]
    float* out1 = out + (size_t)NB * NPIX * NCAT;        // mask        [8,N]
    float* out2 = out1 + NB * NPIX;                      // ncm         [8,N]
    float* out3 = out2 + NB * NPIX;                      // min_d       [8,N]
    float* out4 = out3 + NB * NPIX;                      // neigh_cls   [8,N]

    if (lane == 0) {
        out1[b0 * NPIX + n] = m0 ? 1.0f : 0.0f;
        out2[b0 * NPIX + n] = m0 ? (float)cls0 : (float)(NCAT - 1);
        out3[b0 * NPIX + n] = v0;
        out4[b0 * NPIX + n] = (float)cls0;
    } else if (lane == 1) {
        out1[b1 * NPIX + n] = m1 ? 1.0f : 0.0f;
        out2[b1 * NPIX + n] = m1 ? (float)cls1 : (float)(NCAT - 1);
        out3[b1 * NPIX + n] = v1;
        out4[b1 * NPIX + n] = (float)cls1;
    }
    // one-hot * mask rows: lanes 0..20 -> row b0, lanes 32..52 -> row b1
    if (lane < NCAT) {
        out0[((size_t)b0 * NPIX + n) * NCAT + lane] =
            (m0 && lane == cls0) ? 1.0f : 0.0f;
    } else if (lane >= 32 && lane < 32 + NCAT) {
        int c = lane - 32;
        out0[((size_t)b1 * NPIX + n) * NCAT + c] =
            (m1 && c == cls1) ? 1.0f : 0.0f;
    }
}

extern "C" void kernel_launch(void* const* d_in, const int* in_sizes, int n_in,
                              void* d_out, int out_size, void* d_ws, size_t ws_size,
                              hipStream_t stream) {
    const float* frame = (const float*)d_in[0];
    const float* tmpl  = (const float*)d_in[1];
    const int*   tcls  = (const int*)d_in[2];
    float* outp = (float*)d_out;
    nn_openset_kernel<<<NPIX, 256, 0, stream>>>(frame, tmpl, tcls, outp);
}

// Round 2
// 730.210 us; speedup vs baseline: 1.0754x; 1.0754x over previous
//
#include <hip/hip_runtime.h>

// NNOpenSetClassifier: per-pixel nearest-template classification.
//   frame [8,16384,128] f32, templates [64,16384,128] f32, classes [64] int
// Outputs (concat, all f32): masked_pred [8,N,21], mask [8,N], ncm [8,N],
//                            min_d [8,N], neigh_classes [8,N]
// Memory-bound: ~604 MB traffic -> ~96 us floor at 6.3 TB/s.
//
// R2 change: frame rows staged to LDS too. Hot loop is now pure LDS+VALU --
// no SMEM/VMEM in the loop, so no lgkmcnt(0)/vmcnt drains in the FMA chain.
// Frame LDS reads are wave-uniform-address -> HW broadcast (no bank cost).

#define NPIX      16384
#define DDIM      128
#define NT        64
#define NB        8
#define NCAT      21
#define THRESH    230.0f
#define TS_STRIDE 132   // 128 + 4 pad: 16B-aligned rows (132*4=528=33*16);
                        // lane t hits bank-quad (t+kq)&7 -> 8 lanes/quad, conflict-free

__global__ __launch_bounds__(256, 4) void nn_openset_kernel(
    const float* __restrict__ frame,   // [8, 16384, 128]
    const float* __restrict__ tmpl,    // [64, 16384, 128]
    const int*   __restrict__ tcls,    // [64]
    float* __restrict__ out)
{
    __shared__ float ts[NT * TS_STRIDE];   // 33792 B templates
    __shared__ float fs[NB * TS_STRIDE];   //  4224 B frame rows -> 38016 B total, 4 blk/CU
    const int n   = blockIdx.x;            // pixel index
    const int tid = threadIdx.x;

    // ---- Stage templates[:, n, :] (64x128 f32 = 32 KB) into LDS ----
    #pragma unroll
    for (int i = 0; i < 8; ++i) {
        int q  = tid + (i << 8);        // float4 index 0..2047
        int t  = q >> 5;                // template row
        int c4 = (q & 31) << 2;         // float offset within row
        float4 v = *(const float4*)(tmpl + (size_t)t * (NPIX * DDIM)
                                         + (size_t)n * DDIM + c4);
        *(float4*)(&ts[t * TS_STRIDE + c4]) = v;
    }
    // ---- Stage frame[:, n, :] (8x128 f32 = 4 KB): one float4 per thread ----
    {
        int b  = tid >> 5;              // batch row 0..7
        int c4 = (tid & 31) << 2;
        float4 v = *(const float4*)(frame + ((size_t)b * NPIX + n) * DDIM + c4);
        *(float4*)(&fs[b * TS_STRIDE + c4]) = v;
    }
    __syncthreads();

    // ---- Compute: wave w owns batch rows {2w, 2w+1}; lane = template t ----
    const int lane = tid & 63;
    const int wv   = __builtin_amdgcn_readfirstlane(tid >> 6);  // wave-uniform
    const int b0 = wv * 2, b1 = b0 + 1;
    const float* xp0 = &fs[b0 * TS_STRIDE];   // uniform addr -> LDS broadcast
    const float* xp1 = &fs[b1 * TS_STRIDE];
    const float* tsp = &ts[lane * TS_STRIDE];

    float acc0 = 0.0f, acc1 = 0.0f;
    #pragma unroll 8
    for (int kq = 0; kq < 32; ++kq) {
        float4 tv = *(const float4*)(tsp + (kq << 2));   // ds_read_b128, padded stride
        float4 x0 = *(const float4*)(xp0 + (kq << 2));   // uniform ds_read_b128 (bcast)
        float4 x1 = *(const float4*)(xp1 + (kq << 2));
        float d;
        d = x0.x - tv.x; acc0 = fmaf(d, d, acc0);
        d = x0.y - tv.y; acc0 = fmaf(d, d, acc0);
        d = x0.z - tv.z; acc0 = fmaf(d, d, acc0);
        d = x0.w - tv.w; acc0 = fmaf(d, d, acc0);
        d = x1.x - tv.x; acc1 = fmaf(d, d, acc1);
        d = x1.y - tv.y; acc1 = fmaf(d, d, acc1);
        d = x1.z - tv.z; acc1 = fmaf(d, d, acc1);
        d = x1.w - tv.w; acc1 = fmaf(d, d, acc1);
    }

    // ---- Wave-wide min+argmin over t (tie -> lower t, = jnp.argmin) ----
    float v0 = acc0, v1 = acc1;
    int   i0 = lane, i1 = lane;
    #pragma unroll
    for (int off = 32; off > 0; off >>= 1) {
        float o0 = __shfl_xor(v0, off);
        int  oi0 = __shfl_xor(i0, off);
        if (o0 < v0 || (o0 == v0 && oi0 < i0)) { v0 = o0; i0 = oi0; }
        float o1 = __shfl_xor(v1, off);
        int  oi1 = __shfl_xor(i1, off);
        if (o1 < v1 || (o1 == v1 && oi1 < i1)) { v1 = o1; i1 = oi1; }
    }

    const int  cls0 = tcls[i0];
    const int  cls1 = tcls[i1];
    const bool m0 = (v0 <= THRESH);
    const bool m1 = (v1 <= THRESH);

    float* out0 = out;                                   // masked_pred [8,N,21]
    float* out1 = out + (size_t)NB * NPIX * NCAT;        // mask        [8,N]
    float* out2 = out1 + NB * NPIX;                      // ncm         [8,N]
    float* out3 = out2 + NB * NPIX;                      // min_d       [8,N]
    float* out4 = out3 + NB * NPIX;                      // neigh_cls   [8,N]

    if (lane == 0) {
        out1[b0 * NPIX + n] = m0 ? 1.0f : 0.0f;
        out2[b0 * NPIX + n] = m0 ? (float)cls0 : (float)(NCAT - 1);
        out3[b0 * NPIX + n] = v0;
        out4[b0 * NPIX + n] = (float)cls0;
    } else if (lane == 1) {
        out1[b1 * NPIX + n] = m1 ? 1.0f : 0.0f;
        out2[b1 * NPIX + n] = m1 ? (float)cls1 : (float)(NCAT - 1);
        out3[b1 * NPIX + n] = v1;
        out4[b1 * NPIX + n] = (float)cls1;
    }
    // one-hot * mask rows: lanes 0..20 -> row b0, lanes 32..52 -> row b1
    if (lane < NCAT) {
        out0[((size_t)b0 * NPIX + n) * NCAT + lane] =
            (m0 && lane == cls0) ? 1.0f : 0.0f;
    } else if (lane >= 32 && lane < 32 + NCAT) {
        int c = lane - 32;
        out0[((size_t)b1 * NPIX + n) * NCAT + c] =
            (m1 && c == cls1) ? 1.0f : 0.0f;
    }
}

extern "C" void kernel_launch(void* const* d_in, const int* in_sizes, int n_in,
                              void* d_out, int out_size, void* d_ws, size_t ws_size,
                              hipStream_t stream) {
    const float* frame = (const float*)d_in[0];
    const float* tmpl  = (const float*)d_in[1];
    const int*   tcls  = (const int*)d_in[2];
    float* outp = (float*)d_out;
    nn_openset_kernel<<<NPIX, 256, 0, stream>>>(frame, tmpl, tcls, outp);
}